// Round 16
// baseline (118.709 us; speedup 1.0000x reference)
//
#include <hip/hip_runtime.h>
#include <hip/hip_bf16.h>
#include <cfloat>
#include <cmath>

typedef unsigned short u16;
typedef unsigned int uint;
typedef unsigned long long u64;
typedef __attribute__((ext_vector_type(8))) short bf16x8;
typedef __attribute__((ext_vector_type(4))) float f32x4;

// Problem constants
constexpr int Bn  = 4096;
constexpr int Rn  = 1000;
constexpr int Vn  = 2000;
constexpr int Dn  = 300;
constexpr int FIN = 600;
constexpr int LAT = 512;
constexpr int ZD  = 512;
constexpr int DISK_N = 20;
constexpr float TEMP_INV = 1.0f / 0.07f;

constexpr int KP_X   = 640;  // FIN padded to 128-mult
constexpr int KP_REL = 384;  // Dn padded to 128-mult
constexpr int VP     = 2048; // Vn padded

__device__ inline u16 f2b(float v) {
  __hip_bfloat16 h = __float2bfloat16(v);
  return *reinterpret_cast<u16*>(&h);
}
__device__ inline float b2f(u16 u) {
  return __uint_as_float((uint)u << 16);
}

__device__ __forceinline__ void async_copy16(const u16* g, u16* l) {
  __builtin_amdgcn_global_load_lds(
      (const __attribute__((address_space(1))) void*)g,
      (__attribute__((address_space(3))) void*)l, 16, 0, 0);
}

// ---------------------------------------------------------------------------
struct TSeg {
  const float* src;
  u16* dst;
  int K, N, Kp, mode, tile_end;  // mode0: transpose+convert; mode1: pad
};
struct TSegs6 { TSeg s[6]; };
struct GSeg {
  const u16* A;       // M' x Kp (rows padded to 64-mult)
  const u16* Bt;      // N' x Kp
  const float* bias;
  float* Cf;          // fp32 out (or null)
  u16* Cb;            // bf16 out (or null)
  const u16* xref;    // vae ref (bf16, stride ldc)
  float* part;        // vae partials (non-null => vae mode)
  int M, N, Kp, ldc, act, tiles_n, tile_end;
};
struct GSegs2 { GSeg s[2]; };

// ---- conv task (transpose-convert or pad-convert) --------------------------
__device__ void run_conv(const TSegs6& cs, int bid, u16* lds) {
  float (*tile)[65] = reinterpret_cast<float (*)[65]>(lds);
  const int tid = threadIdx.x;
  int si = 0;
  while (si < 5 && bid >= cs.s[si].tile_end) ++si;
  const TSeg sg = cs.s[si];
  int t0 = (si == 0) ? 0 : cs.s[si - 1].tile_end;
  int t = bid - t0;
  int tiles_k = sg.Kp >> 6;
  int tr0 = (t / tiles_k) << 6;
  int tk0 = (t % tiles_k) << 6;

  if (sg.mode == 0) {
#pragma unroll
    for (int i = 0; i < 16; ++i) {
      int idx = tid + i * 256;
      int ko = idx >> 6, no = idx & 63;
      int gk = tk0 + ko, gn = tr0 + no;
      float v = 0.0f;
      if (gk < sg.K && gn < sg.N) v = sg.src[(size_t)gk * sg.N + gn];
      tile[ko][no] = v;
    }
    __syncthreads();
#pragma unroll
    for (int i = 0; i < 16; ++i) {
      int idx = tid + i * 256;
      int ko = idx & 63, no = idx >> 6;
      sg.dst[(size_t)(tr0 + no) * sg.Kp + tk0 + ko] = f2b(tile[ko][no]);
    }
  } else {
#pragma unroll
    for (int i = 0; i < 16; ++i) {
      int idx = tid + i * 256;
      int mo = idx >> 6, ko = idx & 63;
      int gm = tr0 + mo, gk = tk0 + ko;
      float v = 0.0f;
      if (gm < sg.K && gk < sg.N) v = sg.src[(size_t)gm * sg.N + gk];
      sg.dst[(size_t)gm * sg.Kp + gk] = f2b(v);
    }
  }
}

// ---- topk + gather task (4 rows per task, one per wave) --------------------
__device__ void run_topk(int t, const float* __restrict__ logits,
                         const int* __restrict__ rels,
                         const float* __restrict__ rel_emb,
                         int* __restrict__ pos_keys, int* __restrict__ neg_keys,
                         u16* __restrict__ x_bf, u16* lds) {
  uint (*hist)[256] = reinterpret_cast<uint (*)[256]>(lds);
  const int tid = threadIdx.x;
  const int wv = tid >> 6;
  const int lane = tid & 63;
  const int row = t * 4 + wv;
  const float* rowp = logits + (size_t)row * Rn;

  uint s[16];
#pragma unroll
  for (int i = 0; i < 16; ++i) {
    int idx = i * 64 + lane;
    float v = (idx < Rn) ? rowp[idx] : 0.0f;
    uint u = __float_as_uint(v);
    s[i] = u ^ (uint)(((int)u >> 31) | 0x80000000);
  }
  const bool v15 = (lane < (Rn - 15 * 64));

  uint pref = 0;
  int r = DISK_N;
#pragma unroll
  for (int pass = 0; pass < 4; ++pass) {
    const int shift = 24 - pass * 8;
    *(uint4*)&hist[wv][lane * 4] = make_uint4(0, 0, 0, 0);
    __syncthreads();
#pragma unroll
    for (int i = 0; i < 16; ++i) {
      bool valid = (i < 15) || v15;
      bool match = valid &&
          (pass == 0 || ((s[i] >> (shift + 8)) == (pref >> (shift + 8))));
      if (match) atomicAdd(&hist[wv][(s[i] >> shift) & 255], 1u);
    }
    __syncthreads();
    uint4 c = *(uint4*)&hist[wv][lane * 4];
    uint t1 = c.x + c.y, t2 = t1 + c.z, t3 = t2 + c.w;
    uint sc = t3;
#pragma unroll
    for (int off = 1; off <= 32; off <<= 1) {
      uint o = __shfl_up(sc, off);
      if (lane >= off) sc += o;
    }
    uint excl = sc - t3;
    uint i0 = excl + c.x, i1 = excl + t1, i2 = excl + t2, i3 = excl + t3;
    u64 m = __ballot(i3 >= (uint)r);
    int fl = __ffsll((unsigned long long)m) - 1;
    int j = (i0 >= (uint)r) ? 0 : (i1 >= (uint)r) ? 1 : (i2 >= (uint)r) ? 2 : 3;
    uint bexcl = (j == 0) ? excl : (j == 1) ? i0 : (j == 2) ? i1 : i2;
    int bin = lane * 4 + j;
    bin = __shfl(bin, fl);
    bexcl = __shfl(bexcl, fl);
    r -= (int)bexcl;
    pref |= (uint)bin << shift;
    __syncthreads();
  }
  const uint T = pref;

  int cl = 0;
#pragma unroll
  for (int i = 0; i < 16; ++i) {
    bool valid = (i < 15) || v15;
    if (valid && s[i] < T) cl++;
  }
  uint scl = (uint)cl;
#pragma unroll
  for (int off = 1; off <= 32; off <<= 1) {
    uint o = __shfl_up(scl, off);
    if (lane >= off) scl += o;
  }
  int pos = (int)(scl - (uint)cl);
  int* nk = neg_keys + (size_t)row * DISK_N;
#pragma unroll
  for (int i = 0; i < 16; ++i) {
    bool valid = (i < 15) || v15;
    if (valid && s[i] < T) { nk[pos] = rels[(i * 64 + lane) * 2 + 1]; pos++; }
  }
  {
    int base = DISK_N - r;
    int need = r, taken = 0;
#pragma unroll
    for (int i = 0; i < 16; ++i) {
      if (need > 0) {
        bool valid = (i < 15) || v15;
        bool eq = valid && (s[i] == T);
        u64 mm = __ballot(eq);
        int before = __popcll(mm & ((1ull << lane) - 1ull));
        if (eq && before < need) nk[base + taken + before] = rels[(i * 64 + lane) * 2 + 1];
        int cnt = __popcll(mm);
        int take = cnt < need ? cnt : need;
        need -= take;
        taken += take;
      }
    }
  }

  u64 b1 = 0;
#pragma unroll
  for (int i = 0; i < 16; ++i) {
    bool valid = (i < 15) || v15;
    uint k = valid ? s[i] : 0u;
    u64 p = ((u64)k << 10) | (u64)(1023 - (i * 64 + lane));
    b1 = p > b1 ? p : b1;
  }
#pragma unroll
  for (int off = 1; off < 64; off <<= 1) {
    u64 o = __shfl_xor(b1, off);
    b1 = o > b1 ? o : b1;
  }
  int idx0 = 1023 - (int)(b1 & 1023);
  u64 b2 = 0;
#pragma unroll
  for (int i = 0; i < 16; ++i) {
    int idx = i * 64 + lane;
    bool valid = ((i < 15) || v15) && (idx != idx0);
    uint k = valid ? s[i] : 0u;
    u64 p = ((u64)k << 10) | (u64)(1023 - idx);
    b2 = p > b2 ? p : b2;
  }
#pragma unroll
  for (int off = 1; off < 64; off <<= 1) {
    u64 o = __shfl_xor(b2, off);
    b2 = o > b2 ? o : b2;
  }
  int idx1 = 1023 - (int)(b2 & 1023);

  int k0 = rels[idx0 * 2 + 1];
  int k1 = rels[idx1 * 2 + 1];
  if (lane == 0) {
    pos_keys[row * 2 + 0] = k0;
    pos_keys[row * 2 + 1] = k1;
  }

  const float* e0 = rel_emb + (size_t)k0 * Dn;
  const float* e1 = rel_emb + (size_t)k1 * Dn;
  u16* xbb = x_bf + (size_t)row * KP_X;
  for (int d = lane; d < KP_X; d += 64) {
    float v = 0.0f;
    if (d < Dn) v = e0[d];
    else if (d < FIN) v = e1[d - Dn];
    xbb[d] = f2b(v);
  }
}

// ---- GEMM task: 64x64 tile, 4 waves (2x2), BK=128, SINGLE-buffer LDS ------
// 32 KB LDS -> 5 blocks/CU; 16 MFMA per wave between barrier pairs (2x the
// BK=64 ratio). XOR swizzle chunk ^= (row & 15) applied on both the per-lane
// global source (inverse) and the ds_read (rule #21: same involution).
__device__ void run_gemm(const GSeg& sg, int t, u16* lds) {
  u16* As = lds;           // [64*128] = 16 KB
  u16* Bs = lds + 8192;    // [64*128] = 16 KB

  const int tid = threadIdx.x;
  const int lane = tid & 63;
  const int w = tid >> 6;
  const int wm = (w >> 1) * 32;
  const int wn = (w & 1) * 32;
  const int m0 = (t / sg.tiles_n) * 64;
  const int n0 = (t % sg.tiles_n) * 64;
  const int Kp = sg.Kp;

  // staging: one gload_lds = 4 rows x 128 cols (1 KB). lane -> row (lane>>4)
  // within the 4-row group, chunk (lane&15), source chunk pre-XORed.
  const int rloc4 = lane >> 4;
  const int ch    = lane & 15;

  auto stage = [&](int k0) {
#pragma unroll
    for (int j = 0; j < 4; ++j) {
      int row = w * 16 + j * 4 + rloc4;   // per-lane row within 64
      int gc = ch ^ (row & 15);           // inverse-swizzled chunk
      async_copy16(sg.A + (size_t)(m0 + row) * Kp + k0 + gc * 8,
                   As + (w * 16 + j * 4) * 128);
      async_copy16(sg.Bt + (size_t)(n0 + row) * Kp + k0 + gc * 8,
                   Bs + (w * 16 + j * 4) * 128);
    }
  };

  f32x4 acc[2][2];
#pragma unroll
  for (int i = 0; i < 2; ++i)
#pragma unroll
    for (int j = 0; j < 2; ++j) acc[i][j] = (f32x4)(0.0f);

  const int r = lane & 15;
  const int kq = lane >> 4;

  auto rd = [&](u16* base, int row, int ck) -> bf16x8 {
    return *(const bf16x8*)(base + row * 128 + ((ck ^ (row & 15)) * 8));
  };

  const int NT = Kp >> 7;
  for (int tt = 0; tt < NT; ++tt) {
    stage(tt << 7);
    __syncthreads();  // vmcnt(0) drain + barrier
#pragma unroll
    for (int ks = 0; ks < 4; ++ks) {
      const int ck = ks * 4 + kq;
      bf16x8 a0 = rd(As, wm + r, ck);
      bf16x8 a1 = rd(As, wm + 16 + r, ck);
      bf16x8 b0 = rd(Bs, wn + r, ck);
      bf16x8 b1 = rd(Bs, wn + 16 + r, ck);
      acc[0][0] = __builtin_amdgcn_mfma_f32_16x16x32_bf16(a0, b0, acc[0][0], 0, 0, 0);
      acc[0][1] = __builtin_amdgcn_mfma_f32_16x16x32_bf16(a0, b1, acc[0][1], 0, 0, 0);
      acc[1][0] = __builtin_amdgcn_mfma_f32_16x16x32_bf16(a1, b0, acc[1][0], 0, 0, 0);
      acc[1][1] = __builtin_amdgcn_mfma_f32_16x16x32_bf16(a1, b1, acc[1][1], 0, 0, 0);
    }
    __syncthreads();  // WAR before next stage overwrites
  }

  const int cr = lane >> 4;
  const int cc = lane & 15;
  const bool fuse_vae = (sg.part != nullptr);
  float vsum = 0.0f;
#pragma unroll
  for (int mi = 0; mi < 2; ++mi) {
#pragma unroll
    for (int ni = 0; ni < 2; ++ni) {
      int gn = n0 + wn + ni * 16 + cc;
      if (gn >= sg.N) continue;
      float bv = sg.bias[gn];
#pragma unroll
      for (int rr = 0; rr < 4; ++rr) {
        int gm = m0 + wm + mi * 16 + cr * 4 + rr;
        if (gm >= sg.M) continue;
        float vv = acc[mi][ni][rr] + bv;
        if (sg.act == 1) vv = tanhf(vv);
        else if (sg.act == 2) vv = 1.0f / (1.0f + expf(-vv));
        else if (sg.act == 3) vv = fmaxf(vv, 0.0f);
        if (fuse_vae) {
          float xr = b2f(sg.xref[(size_t)gm * sg.ldc + gn]);
          float d = xr - vv;
          vsum = fmaf(d, d, vsum);
        } else if (sg.Cb) {
          sg.Cb[(size_t)gm * sg.ldc + gn] = f2b(vv);
        } else {
          sg.Cf[(size_t)gm * sg.ldc + gn] = vv;
        }
      }
    }
  }
  if (fuse_vae) {
    float* red = (float*)lds;
    red[tid] = vsum;
    __syncthreads();
    for (int off = 128; off >= 1; off >>= 1) {
      if (tid < off) red[tid] += red[tid + off];
      __syncthreads();
    }
    if (tid == 0) sg.part[t] = red[0];
  }
}

// ---------------------------------------------------------------------------
__global__ __launch_bounds__(256) void prep_kernel(
    TSegs6 cs, int conv_end,
    const float* __restrict__ logits, const int* __restrict__ rels,
    const float* __restrict__ rel_emb,
    int* __restrict__ pos_keys, int* __restrict__ neg_keys,
    u16* __restrict__ x_bf) {
  __shared__ u16 lds[8320];
  if ((int)blockIdx.x < conv_end) {
    run_conv(cs, blockIdx.x, lds);
  } else {
    run_topk(blockIdx.x - conv_end, logits, rels, rel_emb, pos_keys, neg_keys,
             x_bf, lds);
  }
}

// ---------------------------------------------------------------------------
__global__ __launch_bounds__(256) void gemm_conv_kernel(GSegs2 gs, TSegs6 cs) {
  __shared__ u16 lds[16384];  // 32 KB: BK128 gemm; conv uses 16.6 KB of it
  const int bid = blockIdx.x;
  if (bid < gs.s[1].tile_end) {
    const int si = (bid >= gs.s[0].tile_end) ? 1 : 0;
    const GSeg sg = gs.s[si];
    const int t = bid - (si ? gs.s[0].tile_end : 0);
    run_gemm(sg, t, lds);
  } else {
    run_conv(cs, bid - gs.s[1].tile_end, lds);
  }
}

// ---------------------------------------------------------------------------
// csl: ONE row per block; 4 waves split the 21 keys (<=6 each).
// ---------------------------------------------------------------------------
__global__ __launch_bounds__(256) void csl_kernel(
    const float* __restrict__ zp, const float* __restrict__ proj,
    const int* __restrict__ pos_keys, const int* __restrict__ neg_keys,
    float* __restrict__ row_loss) {
  __shared__ float lgs[24];
  const int tid = threadIdx.x;
  const int wv = tid >> 6;
  const int lane = tid & 63;
  const int b = blockIdx.x;

  const float* z = zp + (size_t)b * ZD;
  float zz[8];
#pragma unroll
  for (int q = 0; q < 2; ++q) {
    int base = (lane + q * 64) * 4;
    float2 a = *(const float2*)(z + base);
    float2 c = *(const float2*)(z + base + 2);
    zz[q * 4 + 0] = a.x; zz[q * 4 + 1] = a.y;
    zz[q * 4 + 2] = c.x; zz[q * 4 + 3] = c.y;
  }

  for (int k = wv; k < 21; k += 4) {
    int key = (k == 0) ? pos_keys[b * 2] : neg_keys[b * DISK_N + (k - 1)];
    const float4* p4 = (const float4*)(proj + (size_t)key * ZD);
    float4 pa = p4[lane];
    float4 pb = p4[lane + 64];
    float acc = zz[0] * pa.x;
    acc = fmaf(zz[1], pa.y, acc);
    acc = fmaf(zz[2], pa.z, acc);
    acc = fmaf(zz[3], pa.w, acc);
    acc = fmaf(zz[4], pb.x, acc);
    acc = fmaf(zz[5], pb.y, acc);
    acc = fmaf(zz[6], pb.z, acc);
    acc = fmaf(zz[7], pb.w, acc);
#pragma unroll
    for (int off = 32; off >= 1; off >>= 1) acc += __shfl_xor(acc, off);
    if (lane == 0) lgs[k] = acc * TEMP_INV;
  }
  __syncthreads();

  if (wv == 0) {
    float v = (lane < 21) ? lgs[lane] : -FLT_MAX;
    float m = v;
#pragma unroll
    for (int off = 32; off >= 1; off >>= 1) m = fmaxf(m, __shfl_xor(m, off));
    float e = (lane < 21) ? expf(v - m) : 0.0f;
    float se = e;
#pragma unroll
    for (int off = 32; off >= 1; off >>= 1) se += __shfl_xor(se, off);
    if (lane == 0) row_loss[b] = m + logf(se) - lgs[0];
  }
}

// ---------------------------------------------------------------------------
__global__ __launch_bounds__(256) void finalize_kernel(
    const float* __restrict__ vae_partials, int n_vae,
    const float* __restrict__ row_loss, int n_rows, float* __restrict__ out) {
  __shared__ float red[256];
  const int tid = threadIdx.x;

  float s = 0.0f;
  for (int i = tid; i < n_vae; i += 256) s += vae_partials[i];
  red[tid] = s;
  __syncthreads();
  for (int off = 128; off >= 1; off >>= 1) {
    if (tid < off) red[tid] += red[tid + off];
    __syncthreads();
  }
  float loss_vae = red[0] * (1.0f / (float)FIN);
  __syncthreads();

  float s2 = 0.0f;
  for (int i = tid; i < n_rows; i += 256) s2 += row_loss[i];
  red[tid] = s2;
  __syncthreads();
  for (int off = 128; off >= 1; off >>= 1) {
    if (tid < off) red[tid] += red[tid + off];
    __syncthreads();
  }
  if (tid == 0) {
    out[0] = loss_vae;
    out[1] = red[0];
  }
  for (int i = tid; i < ZD; i += 256) out[2 + i] = 0.0f;
}

// ---------------------------------------------------------------------------
extern "C" void kernel_launch(void* const* d_in, const int* in_sizes, int n_in,
                              void* d_out, int out_size, void* d_ws,
                              size_t ws_size, hipStream_t stream) {
  const float* logits = (const float*)d_in[0];
  const int*   rels   = (const int*)d_in[1];
  const float* rel_emb= (const float*)d_in[2];
  const float* We1 = (const float*)d_in[3];  const float* be1 = (const float*)d_in[4];
  const float* We2 = (const float*)d_in[5];  const float* be2 = (const float*)d_in[6];
  const float* Wd1 = (const float*)d_in[7];  const float* bd1 = (const float*)d_in[8];
  const float* Wd2 = (const float*)d_in[9];  const float* bd2 = (const float*)d_in[10];
  const float* Wz1 = (const float*)d_in[11]; const float* bz1 = (const float*)d_in[12];
  const float* Wz2 = (const float*)d_in[13]; const float* bz2 = (const float*)d_in[14];
  const float* Wk1 = (const float*)d_in[19]; const float* bk1 = (const float*)d_in[20];
  const float* Wk2 = (const float*)d_in[21]; const float* bk2 = (const float*)d_in[22];

  float* out = (float*)d_out;

  char* ws = (char*)d_ws;
  size_t off = 0;
  auto walloc = [&](size_t bytes) -> void* {
    void* p = ws + off;
    off = (off + bytes + 255) & ~(size_t)255;
    return p;
  };
  int*   pos_keys = (int*)walloc((size_t)Bn * 2 * sizeof(int));
  int*   neg_keys = (int*)walloc((size_t)Bn * DISK_N * sizeof(int));
  float* proj     = (float*)walloc((size_t)Vn * ZD * sizeof(float));
  u16*   x_bf     = (u16*)walloc((size_t)Bn * KP_X * 2);
  u16*   t1       = (u16*)walloc((size_t)Bn * LAT * 2);
  u16*   zb       = (u16*)walloc((size_t)Bn * LAT * 2);
  u16*   t2       = (u16*)walloc((size_t)Bn * LAT * 2);
  u16*   t3       = (u16*)walloc((size_t)Bn * LAT * 2);
  u16*   th_bf    = (u16*)walloc((size_t)VP * LAT * 2);
  u16*   rel_bf   = (u16*)walloc((size_t)VP * KP_REL * 2);
  u16*   We1T     = (u16*)walloc((size_t)LAT * KP_X * 2);
  u16*   We2T     = (u16*)walloc((size_t)LAT * LAT * 2);
  u16*   Wd1T     = (u16*)walloc((size_t)LAT * LAT * 2);
  u16*   Wd2T     = (u16*)walloc((size_t)KP_X * LAT * 2);
  u16*   Wz1T     = (u16*)walloc((size_t)LAT * LAT * 2);
  u16*   Wz2T     = (u16*)walloc((size_t)LAT * LAT * 2);
  u16*   Wk1T     = (u16*)walloc((size_t)LAT * KP_REL * 2);
  u16*   Wk2T     = (u16*)walloc((size_t)LAT * LAT * 2);
  float* vae_part = (float*)walloc(1024 * sizeof(float));
  float* row_loss = (float*)walloc((size_t)Bn * sizeof(float));
  (void)ws_size; (void)in_sizes; (void)n_in; (void)out_size;

  float* zp_out = out + 2 + ZD;

  auto mk_tseg = [](const float* s, u16* d, int K, int N, int Kp, int mode) {
    TSeg t;
    t.src = s; t.dst = d; t.K = K; t.N = N; t.Kp = Kp; t.mode = mode;
    t.tile_end = 0;
    return t;
  };
  auto tseg_tiles = [](const TSeg& t) {
    int rows = (t.mode == 0) ? ((t.N + 63) & ~63) : VP;
    return (rows >> 6) * (t.Kp >> 6);
  };
  auto finish_tsegs = [&](TSegs6& c, int n) {
    int acc = 0;
    for (int i = 0; i < 6; ++i) {
      if (i < n) acc += tseg_tiles(c.s[i]);
      c.s[i].tile_end = acc;
    }
    return acc;
  };

  // ---- prep: We1T, Wk1T, rel pad + topk ----
  TSegs6 pc;
  pc.s[0] = mk_tseg(We1, We1T, FIN, LAT, KP_X, 0);
  pc.s[1] = mk_tseg(Wk1, Wk1T, Dn, LAT, KP_REL, 0);
  pc.s[2] = mk_tseg(rel_emb, rel_bf, Vn, Dn, KP_REL, 1);
  int prep_conv = finish_tsegs(pc, 3);
  prep_kernel<<<prep_conv + Bn / 4, 256, 0, stream>>>(
      pc, prep_conv, logits, rels, rel_emb, pos_keys, neg_keys, x_bf);

  auto mk_gseg = [](const u16* A, const u16* Bt, const float* bias, float* Cf,
                    u16* Cb, const u16* xref, float* part, int M, int N,
                    int Kp, int ldc, int act, int tiles_n) {
    GSeg g;
    g.A = A; g.Bt = Bt; g.bias = bias; g.Cf = Cf; g.Cb = Cb;
    g.xref = xref; g.part = part;
    g.M = M; g.N = N; g.Kp = Kp; g.ldc = ldc; g.act = act;
    g.tiles_n = tiles_n; g.tile_end = 0;
    return g;
  };
  auto gseg_tiles = [](const GSeg& g) {
    return ((g.M + 63) / 64) * g.tiles_n;
  };
  TSegs6 none;
  finish_tsegs(none, 0);
  auto launch_phase = [&](GSeg a, GSeg b, TSegs6 cs, int nconv) {
    GSegs2 gs;
    a.tile_end = gseg_tiles(a);
    b.tile_end = a.tile_end + gseg_tiles(b);
    gs.s[0] = a; gs.s[1] = b;
    int conv_tiles = finish_tsegs(cs, nconv);
    gemm_conv_kernel<<<gs.s[1].tile_end + conv_tiles, 256, 0, stream>>>(gs, cs);
  };

  // A: th = relu(rel_bf@Wk1+bk1) || t1 = tanh(x_bf@We1+be1)  (+6 transposes)
  TSegs6 ac;
  ac.s[0] = mk_tseg(We2, We2T, LAT, LAT, LAT, 0);
  ac.s[1] = mk_tseg(Wd1, Wd1T, LAT, LAT, LAT, 0);
  ac.s[2] = mk_tseg(Wd2, Wd2T, LAT, FIN, LAT, 0);
  ac.s[3] = mk_tseg(Wz1, Wz1T, LAT, LAT, LAT, 0);
  ac.s[4] = mk_tseg(Wz2, Wz2T, LAT, LAT, LAT, 0);
  ac.s[5] = mk_tseg(Wk2, Wk2T, LAT, LAT, LAT, 0);
  launch_phase(
      mk_gseg(rel_bf, Wk1T, bk1, nullptr, th_bf, nullptr, nullptr, Vn, LAT, KP_REL, LAT, 3, 8),
      mk_gseg(x_bf, We1T, be1, nullptr, t1, nullptr, nullptr, Bn, LAT, KP_X, LAT, 1, 8),
      ac, 6);
  // B: proj = th@Wk2+bk2 || zb = tanh(t1@We2+be2)
  launch_phase(
      mk_gseg(th_bf, Wk2T, bk2, proj, nullptr, nullptr, nullptr, Vn, ZD, LAT, ZD, 0, 8),
      mk_gseg(t1, We2T, be2, nullptr, zb, nullptr, nullptr, Bn, ZD, LAT, ZD, 1, 8),
      none, 0);
  // C: t2 = tanh(zb@Wd1+bd1) || t3 = relu(zb@Wz1+bz1)
  launch_phase(
      mk_gseg(zb, Wd1T, bd1, nullptr, t2, nullptr, nullptr, Bn, LAT, ZD, LAT, 1, 8),
      mk_gseg(zb, Wz1T, bz1, nullptr, t3, nullptr, nullptr, Bn, LAT, ZD, LAT, 3, 8),
      none, 0);
  // D: vae partials from sigmoid(t2@Wd2+bd2) vs x_bf || zp = t3@Wz2+bz2
  launch_phase(
      mk_gseg(t2, Wd2T, bd2, nullptr, nullptr, x_bf, vae_part, Bn, FIN, LAT, KP_X, 2, KP_X / 64),
      mk_gseg(t3, Wz2T, bz2, zp_out, nullptr, nullptr, nullptr, Bn, ZD, LAT, ZD, 0, 8),
      none, 0);

  const int n_vae_parts = (Bn / 64) * (KP_X / 64);  // 640

  csl_kernel<<<Bn, 256, 0, stream>>>(zp_out, proj, pos_keys, neg_keys, row_loss);
  finalize_kernel<<<1, 256, 0, stream>>>(vae_part, n_vae_parts, row_loss, Bn, out);
}

// Round 17
// 113.990 us; speedup vs baseline: 1.0414x; 1.0414x over previous
//
#include <hip/hip_runtime.h>
#include <hip/hip_bf16.h>
#include <cfloat>
#include <cmath>

typedef unsigned short u16;
typedef unsigned int uint;
typedef unsigned long long u64;
typedef __attribute__((ext_vector_type(8))) short bf16x8;
typedef __attribute__((ext_vector_type(4))) float f32x4;

// Problem constants
constexpr int Bn  = 4096;
constexpr int Rn  = 1000;
constexpr int Vn  = 2000;
constexpr int Dn  = 300;
constexpr int FIN = 600;
constexpr int LAT = 512;
constexpr int ZD  = 512;
constexpr int DISK_N = 20;
constexpr float TEMP_INV = 1.0f / 0.07f;

constexpr int KP_X   = 640;  // FIN padded to 64-mult
constexpr int KP_REL = 320;  // Dn padded
constexpr int VP     = 2048; // Vn padded

__device__ inline u16 f2b(float v) {
  __hip_bfloat16 h = __float2bfloat16(v);
  return *reinterpret_cast<u16*>(&h);
}
__device__ inline float b2f(u16 u) {
  return __uint_as_float((uint)u << 16);
}

__device__ __forceinline__ void async_copy16(const u16* g, u16* l) {
  __builtin_amdgcn_global_load_lds(
      (const __attribute__((address_space(1))) void*)g,
      (__attribute__((address_space(3))) void*)l, 16, 0, 0);
}

// ---------------------------------------------------------------------------
struct TSeg {
  const float* src;
  u16* dst;
  int K, N, Kp, mode, tile_end;  // mode0: transpose+convert; mode1: pad
};
struct TSegs6 { TSeg s[6]; };
struct GSeg {
  const u16* A;       // M' x Kp (rows padded to 64-mult)
  const u16* Bt;      // N' x Kp
  const float* bias;
  float* Cf;          // fp32 out (or null)
  u16* Cb;            // bf16 out (or null)
  const u16* xref;    // vae ref (bf16, stride ldc)
  float* part;        // vae partials (non-null => vae mode)
  int M, N, Kp, ldc, act, tiles_n, tile_end;
};
struct GSegs2 { GSeg s[2]; };

// ---- conv task (transpose-convert or pad-convert) --------------------------
__device__ void run_conv(const TSegs6& cs, int bid, u16* lds) {
  float (*tile)[65] = reinterpret_cast<float (*)[65]>(lds);
  const int tid = threadIdx.x;
  int si = 0;
  while (si < 5 && bid >= cs.s[si].tile_end) ++si;
  const TSeg sg = cs.s[si];
  int t0 = (si == 0) ? 0 : cs.s[si - 1].tile_end;
  int t = bid - t0;
  int tiles_k = sg.Kp >> 6;
  int tr0 = (t / tiles_k) << 6;
  int tk0 = (t % tiles_k) << 6;

  if (sg.mode == 0) {
#pragma unroll
    for (int i = 0; i < 16; ++i) {
      int idx = tid + i * 256;
      int ko = idx >> 6, no = idx & 63;
      int gk = tk0 + ko, gn = tr0 + no;
      float v = 0.0f;
      if (gk < sg.K && gn < sg.N) v = sg.src[(size_t)gk * sg.N + gn];
      tile[ko][no] = v;
    }
    __syncthreads();
#pragma unroll
    for (int i = 0; i < 16; ++i) {
      int idx = tid + i * 256;
      int ko = idx & 63, no = idx >> 6;
      sg.dst[(size_t)(tr0 + no) * sg.Kp + tk0 + ko] = f2b(tile[ko][no]);
    }
  } else {
#pragma unroll
    for (int i = 0; i < 16; ++i) {
      int idx = tid + i * 256;
      int mo = idx >> 6, ko = idx & 63;
      int gm = tr0 + mo, gk = tk0 + ko;
      float v = 0.0f;
      if (gm < sg.K && gk < sg.N) v = sg.src[(size_t)gm * sg.N + gk];
      sg.dst[(size_t)gm * sg.Kp + gk] = f2b(v);
    }
  }
}

// ---- topk + gather task (4 rows per task, one per wave) --------------------
__device__ void run_topk(int t, const float* __restrict__ logits,
                         const int* __restrict__ rels,
                         const float* __restrict__ rel_emb,
                         int* __restrict__ pos_keys, int* __restrict__ neg_keys,
                         u16* __restrict__ x_bf, u16* lds) {
  uint (*hist)[256] = reinterpret_cast<uint (*)[256]>(lds);
  const int tid = threadIdx.x;
  const int wv = tid >> 6;
  const int lane = tid & 63;
  const int row = t * 4 + wv;
  const float* rowp = logits + (size_t)row * Rn;

  uint s[16];
#pragma unroll
  for (int i = 0; i < 16; ++i) {
    int idx = i * 64 + lane;
    float v = (idx < Rn) ? rowp[idx] : 0.0f;
    uint u = __float_as_uint(v);
    s[i] = u ^ (uint)(((int)u >> 31) | 0x80000000);
  }
  const bool v15 = (lane < (Rn - 15 * 64));

  uint pref = 0;
  int r = DISK_N;
#pragma unroll
  for (int pass = 0; pass < 4; ++pass) {
    const int shift = 24 - pass * 8;
    *(uint4*)&hist[wv][lane * 4] = make_uint4(0, 0, 0, 0);
    __syncthreads();
#pragma unroll
    for (int i = 0; i < 16; ++i) {
      bool valid = (i < 15) || v15;
      bool match = valid &&
          (pass == 0 || ((s[i] >> (shift + 8)) == (pref >> (shift + 8))));
      if (match) atomicAdd(&hist[wv][(s[i] >> shift) & 255], 1u);
    }
    __syncthreads();
    uint4 c = *(uint4*)&hist[wv][lane * 4];
    uint t1 = c.x + c.y, t2 = t1 + c.z, t3 = t2 + c.w;
    uint sc = t3;
#pragma unroll
    for (int off = 1; off <= 32; off <<= 1) {
      uint o = __shfl_up(sc, off);
      if (lane >= off) sc += o;
    }
    uint excl = sc - t3;
    uint i0 = excl + c.x, i1 = excl + t1, i2 = excl + t2, i3 = excl + t3;
    u64 m = __ballot(i3 >= (uint)r);
    int fl = __ffsll((unsigned long long)m) - 1;
    int j = (i0 >= (uint)r) ? 0 : (i1 >= (uint)r) ? 1 : (i2 >= (uint)r) ? 2 : 3;
    uint bexcl = (j == 0) ? excl : (j == 1) ? i0 : (j == 2) ? i1 : i2;
    int bin = lane * 4 + j;
    bin = __shfl(bin, fl);
    bexcl = __shfl(bexcl, fl);
    r -= (int)bexcl;
    pref |= (uint)bin << shift;
    __syncthreads();
  }
  const uint T = pref;

  int cl = 0;
#pragma unroll
  for (int i = 0; i < 16; ++i) {
    bool valid = (i < 15) || v15;
    if (valid && s[i] < T) cl++;
  }
  uint scl = (uint)cl;
#pragma unroll
  for (int off = 1; off <= 32; off <<= 1) {
    uint o = __shfl_up(scl, off);
    if (lane >= off) scl += o;
  }
  int pos = (int)(scl - (uint)cl);
  int* nk = neg_keys + (size_t)row * DISK_N;
#pragma unroll
  for (int i = 0; i < 16; ++i) {
    bool valid = (i < 15) || v15;
    if (valid && s[i] < T) { nk[pos] = rels[(i * 64 + lane) * 2 + 1]; pos++; }
  }
  {
    int base = DISK_N - r;
    int need = r, taken = 0;
#pragma unroll
    for (int i = 0; i < 16; ++i) {
      if (need > 0) {
        bool valid = (i < 15) || v15;
        bool eq = valid && (s[i] == T);
        u64 mm = __ballot(eq);
        int before = __popcll(mm & ((1ull << lane) - 1ull));
        if (eq && before < need) nk[base + taken + before] = rels[(i * 64 + lane) * 2 + 1];
        int cnt = __popcll(mm);
        int take = cnt < need ? cnt : need;
        need -= take;
        taken += take;
      }
    }
  }

  u64 b1 = 0;
#pragma unroll
  for (int i = 0; i < 16; ++i) {
    bool valid = (i < 15) || v15;
    uint k = valid ? s[i] : 0u;
    u64 p = ((u64)k << 10) | (u64)(1023 - (i * 64 + lane));
    b1 = p > b1 ? p : b1;
  }
#pragma unroll
  for (int off = 1; off < 64; off <<= 1) {
    u64 o = __shfl_xor(b1, off);
    b1 = o > b1 ? o : b1;
  }
  int idx0 = 1023 - (int)(b1 & 1023);
  u64 b2 = 0;
#pragma unroll
  for (int i = 0; i < 16; ++i) {
    int idx = i * 64 + lane;
    bool valid = ((i < 15) || v15) && (idx != idx0);
    uint k = valid ? s[i] : 0u;
    u64 p = ((u64)k << 10) | (u64)(1023 - idx);
    b2 = p > b2 ? p : b2;
  }
#pragma unroll
  for (int off = 1; off < 64; off <<= 1) {
    u64 o = __shfl_xor(b2, off);
    b2 = o > b2 ? o : b2;
  }
  int idx1 = 1023 - (int)(b2 & 1023);

  int k0 = rels[idx0 * 2 + 1];
  int k1 = rels[idx1 * 2 + 1];
  if (lane == 0) {
    pos_keys[row * 2 + 0] = k0;
    pos_keys[row * 2 + 1] = k1;
  }

  const float* e0 = rel_emb + (size_t)k0 * Dn;
  const float* e1 = rel_emb + (size_t)k1 * Dn;
  u16* xbb = x_bf + (size_t)row * KP_X;
  for (int d = lane; d < KP_X; d += 64) {
    float v = 0.0f;
    if (d < Dn) v = e0[d];
    else if (d < FIN) v = e1[d - Dn];
    xbb[d] = f2b(v);
  }
}

// ---- GEMM task: 64x64 tile, 4 waves (2x2), BK=64, SINGLE-buffer LDS -------
// 16 KB LDS + launch_bounds(256,8) -> 8 blocks/CU (32 waves): TLP hides the
// per-iter stage latency. (Established local optimum: BK128/dbuf/big-tile/
// reg-direct all measured worse; occupancy is the dominant lever here.)
__device__ void run_gemm(const GSeg& sg, int t, u16* lds) {
  u16* As = lds;           // [4096]
  u16* Bs = lds + 4096;    // [4096]

  const int tid = threadIdx.x;
  const int lane = tid & 63;
  const int w = tid >> 6;
  const int wm = (w >> 1) * 32;
  const int wn = (w & 1) * 32;
  const int m0 = (t / sg.tiles_n) * 64;
  const int n0 = (t % sg.tiles_n) * 64;
  const int Kp = sg.Kp;

  const int rA = lane >> 3;
  const int cC = ((lane & 7) ^ rA) * 8;
  const u16* gA = sg.A + (size_t)(m0 + w * 16 + rA) * Kp + cC;
  const u16* gB = sg.Bt + (size_t)(n0 + w * 16 + rA) * Kp + cC;

  auto stage = [&](int k0) {
#pragma unroll
    for (int j = 0; j < 2; ++j) {
      async_copy16(gA + (size_t)j * 8 * Kp + k0, As + (w * 16 + j * 8) * 64);
      async_copy16(gB + (size_t)j * 8 * Kp + k0, Bs + (w * 16 + j * 8) * 64);
    }
  };

  f32x4 acc[2][2];
#pragma unroll
  for (int i = 0; i < 2; ++i)
#pragma unroll
    for (int j = 0; j < 2; ++j) acc[i][j] = (f32x4)(0.0f);

  const int r = lane & 15;
  const int kq = lane >> 4;

  const int NT = Kp >> 6;
  for (int tt = 0; tt < NT; ++tt) {
    stage(tt << 6);
    __syncthreads();  // compiler emits vmcnt(0) drain before barrier
#pragma unroll
    for (int ks = 0; ks < 2; ++ks) {
      const int kk = ks * 32 + kq * 8;
      const int xm = (r & 7) << 3;
      bf16x8 a0 = *(const bf16x8*)(As + (wm + r) * 64 + (kk ^ xm));
      bf16x8 a1 = *(const bf16x8*)(As + (wm + 16 + r) * 64 + (kk ^ xm));
      bf16x8 b0 = *(const bf16x8*)(Bs + (wn + r) * 64 + (kk ^ xm));
      bf16x8 b1 = *(const bf16x8*)(Bs + (wn + 16 + r) * 64 + (kk ^ xm));
      acc[0][0] = __builtin_amdgcn_mfma_f32_16x16x32_bf16(a0, b0, acc[0][0], 0, 0, 0);
      acc[0][1] = __builtin_amdgcn_mfma_f32_16x16x32_bf16(a0, b1, acc[0][1], 0, 0, 0);
      acc[1][0] = __builtin_amdgcn_mfma_f32_16x16x32_bf16(a1, b0, acc[1][0], 0, 0, 0);
      acc[1][1] = __builtin_amdgcn_mfma_f32_16x16x32_bf16(a1, b1, acc[1][1], 0, 0, 0);
    }
    __syncthreads();  // WAR before next stage overwrites
  }

  const int cr = lane >> 4;
  const int cc = lane & 15;
  const bool fuse_vae = (sg.part != nullptr);
  float vsum = 0.0f;
#pragma unroll
  for (int mi = 0; mi < 2; ++mi) {
#pragma unroll
    for (int ni = 0; ni < 2; ++ni) {
      int gn = n0 + wn + ni * 16 + cc;
      if (gn >= sg.N) continue;
      float bv = sg.bias[gn];
#pragma unroll
      for (int rr = 0; rr < 4; ++rr) {
        int gm = m0 + wm + mi * 16 + cr * 4 + rr;
        if (gm >= sg.M) continue;
        float vv = acc[mi][ni][rr] + bv;
        if (sg.act == 1) vv = tanhf(vv);
        else if (sg.act == 2) vv = 1.0f / (1.0f + expf(-vv));
        else if (sg.act == 3) vv = fmaxf(vv, 0.0f);
        if (fuse_vae) {
          float xr = b2f(sg.xref[(size_t)gm * sg.ldc + gn]);
          float d = xr - vv;
          vsum = fmaf(d, d, vsum);
        } else if (sg.Cb) {
          sg.Cb[(size_t)gm * sg.ldc + gn] = f2b(vv);
        } else {
          sg.Cf[(size_t)gm * sg.ldc + gn] = vv;
        }
      }
    }
  }
  if (fuse_vae) {
    float* red = (float*)lds;
    red[tid] = vsum;
    __syncthreads();
    for (int off = 128; off >= 1; off >>= 1) {
      if (tid < off) red[tid] += red[tid + off];
      __syncthreads();
    }
    if (tid == 0) sg.part[t] = red[0];
  }
}

// ---------------------------------------------------------------------------
__global__ __launch_bounds__(256) void prep_kernel(
    TSegs6 cs, int conv_end,
    const float* __restrict__ logits, const int* __restrict__ rels,
    const float* __restrict__ rel_emb,
    int* __restrict__ pos_keys, int* __restrict__ neg_keys,
    u16* __restrict__ x_bf) {
  __shared__ u16 lds[8320];
  if ((int)blockIdx.x < conv_end) {
    run_conv(cs, blockIdx.x, lds);
  } else {
    run_topk(blockIdx.x - conv_end, logits, rels, rel_emb, pos_keys, neg_keys,
             x_bf, lds);
  }
}

// ---------------------------------------------------------------------------
__global__ __launch_bounds__(256, 8) void gemm_conv_kernel(GSegs2 gs, TSegs6 cs) {
  __shared__ u16 lds[8320];  // 16.6 KB: gemm uses 16 KB, conv uses all
  const int bid = blockIdx.x;
  if (bid < gs.s[1].tile_end) {
    const int si = (bid >= gs.s[0].tile_end) ? 1 : 0;
    const GSeg sg = gs.s[si];
    const int t = bid - (si ? gs.s[0].tile_end : 0);
    run_gemm(sg, t, lds);
  } else {
    run_conv(cs, bid - gs.s[1].tile_end, lds);
  }
}

// ---------------------------------------------------------------------------
// csl: ONE row per block, 8 waves (512 thr) split the 21 keys (<=3 each) --
// halves the per-wave serial gather-latency chain vs 4 waves.
// ---------------------------------------------------------------------------
__global__ __launch_bounds__(512) void csl_kernel(
    const float* __restrict__ zp, const float* __restrict__ proj,
    const int* __restrict__ pos_keys, const int* __restrict__ neg_keys,
    float* __restrict__ row_loss) {
  __shared__ float lgs[24];
  const int tid = threadIdx.x;
  const int wv = tid >> 6;
  const int lane = tid & 63;
  const int b = blockIdx.x;

  const float* z = zp + (size_t)b * ZD;
  float zz[8];
#pragma unroll
  for (int q = 0; q < 2; ++q) {
    int base = (lane + q * 64) * 4;
    float2 a = *(const float2*)(z + base);
    float2 c = *(const float2*)(z + base + 2);
    zz[q * 4 + 0] = a.x; zz[q * 4 + 1] = a.y;
    zz[q * 4 + 2] = c.x; zz[q * 4 + 3] = c.y;
  }

  for (int k = wv; k < 21; k += 8) {
    int key = (k == 0) ? pos_keys[b * 2] : neg_keys[b * DISK_N + (k - 1)];
    const float4* p4 = (const float4*)(proj + (size_t)key * ZD);
    float4 pa = p4[lane];
    float4 pb = p4[lane + 64];
    float acc = zz[0] * pa.x;
    acc = fmaf(zz[1], pa.y, acc);
    acc = fmaf(zz[2], pa.z, acc);
    acc = fmaf(zz[3], pa.w, acc);
    acc = fmaf(zz[4], pb.x, acc);
    acc = fmaf(zz[5], pb.y, acc);
    acc = fmaf(zz[6], pb.z, acc);
    acc = fmaf(zz[7], pb.w, acc);
#pragma unroll
    for (int off = 32; off >= 1; off >>= 1) acc += __shfl_xor(acc, off);
    if (lane == 0) lgs[k] = acc * TEMP_INV;
  }
  __syncthreads();

  if (wv == 0) {
    float v = (lane < 21) ? lgs[lane] : -FLT_MAX;
    float m = v;
#pragma unroll
    for (int off = 32; off >= 1; off >>= 1) m = fmaxf(m, __shfl_xor(m, off));
    float e = (lane < 21) ? expf(v - m) : 0.0f;
    float se = e;
#pragma unroll
    for (int off = 32; off >= 1; off >>= 1) se += __shfl_xor(se, off);
    if (lane == 0) row_loss[b] = m + logf(se) - lgs[0];
  }
}

// ---------------------------------------------------------------------------
__global__ __launch_bounds__(256) void finalize_kernel(
    const float* __restrict__ vae_partials, int n_vae,
    const float* __restrict__ row_loss, int n_rows, float* __restrict__ out) {
  __shared__ float red[256];
  const int tid = threadIdx.x;

  float s = 0.0f;
  for (int i = tid; i < n_vae; i += 256) s += vae_partials[i];
  red[tid] = s;
  __syncthreads();
  for (int off = 128; off >= 1; off >>= 1) {
    if (tid < off) red[tid] += red[tid + off];
    __syncthreads();
  }
  float loss_vae = red[0] * (1.0f / (float)FIN);
  __syncthreads();

  float s2 = 0.0f;
  for (int i = tid; i < n_rows; i += 256) s2 += row_loss[i];
  red[tid] = s2;
  __syncthreads();
  for (int off = 128; off >= 1; off >>= 1) {
    if (tid < off) red[tid] += red[tid + off];
    __syncthreads();
  }
  if (tid == 0) {
    out[0] = loss_vae;
    out[1] = red[0];
  }
  for (int i = tid; i < ZD; i += 256) out[2 + i] = 0.0f;
}

// ---------------------------------------------------------------------------
extern "C" void kernel_launch(void* const* d_in, const int* in_sizes, int n_in,
                              void* d_out, int out_size, void* d_ws,
                              size_t ws_size, hipStream_t stream) {
  const float* logits = (const float*)d_in[0];
  const int*   rels   = (const int*)d_in[1];
  const float* rel_emb= (const float*)d_in[2];
  const float* We1 = (const float*)d_in[3];  const float* be1 = (const float*)d_in[4];
  const float* We2 = (const float*)d_in[5];  const float* be2 = (const float*)d_in[6];
  const float* Wd1 = (const float*)d_in[7];  const float* bd1 = (const float*)d_in[8];
  const float* Wd2 = (const float*)d_in[9];  const float* bd2 = (const float*)d_in[10];
  const float* Wz1 = (const float*)d_in[11]; const float* bz1 = (const float*)d_in[12];
  const float* Wz2 = (const float*)d_in[13]; const float* bz2 = (const float*)d_in[14];
  const float* Wk1 = (const float*)d_in[19]; const float* bk1 = (const float*)d_in[20];
  const float* Wk2 = (const float*)d_in[21]; const float* bk2 = (const float*)d_in[22];

  float* out = (float*)d_out;

  char* ws = (char*)d_ws;
  size_t off = 0;
  auto walloc = [&](size_t bytes) -> void* {
    void* p = ws + off;
    off = (off + bytes + 255) & ~(size_t)255;
    return p;
  };
  int*   pos_keys = (int*)walloc((size_t)Bn * 2 * sizeof(int));
  int*   neg_keys = (int*)walloc((size_t)Bn * DISK_N * sizeof(int));
  float* proj     = (float*)walloc((size_t)Vn * ZD * sizeof(float));
  u16*   x_bf     = (u16*)walloc((size_t)Bn * KP_X * 2);
  u16*   t1       = (u16*)walloc((size_t)Bn * LAT * 2);
  u16*   zb       = (u16*)walloc((size_t)Bn * LAT * 2);
  u16*   t2       = (u16*)walloc((size_t)Bn * LAT * 2);
  u16*   t3       = (u16*)walloc((size_t)Bn * LAT * 2);
  u16*   th_bf    = (u16*)walloc((size_t)VP * LAT * 2);
  u16*   rel_bf   = (u16*)walloc((size_t)VP * KP_REL * 2);
  u16*   We1T     = (u16*)walloc((size_t)LAT * KP_X * 2);
  u16*   We2T     = (u16*)walloc((size_t)LAT * LAT * 2);
  u16*   Wd1T     = (u16*)walloc((size_t)LAT * LAT * 2);
  u16*   Wd2T     = (u16*)walloc((size_t)KP_X * LAT * 2);
  u16*   Wz1T     = (u16*)walloc((size_t)LAT * LAT * 2);
  u16*   Wz2T     = (u16*)walloc((size_t)LAT * LAT * 2);
  u16*   Wk1T     = (u16*)walloc((size_t)LAT * KP_REL * 2);
  u16*   Wk2T     = (u16*)walloc((size_t)LAT * LAT * 2);
  float* vae_part = (float*)walloc(1024 * sizeof(float));
  float* row_loss = (float*)walloc((size_t)Bn * sizeof(float));
  (void)ws_size; (void)in_sizes; (void)n_in; (void)out_size;

  float* zp_out = out + 2 + ZD;

  auto mk_tseg = [](const float* s, u16* d, int K, int N, int Kp, int mode) {
    TSeg t;
    t.src = s; t.dst = d; t.K = K; t.N = N; t.Kp = Kp; t.mode = mode;
    t.tile_end = 0;
    return t;
  };
  auto tseg_tiles = [](const TSeg& t) {
    int rows = (t.mode == 0) ? ((t.N + 63) & ~63) : VP;
    return (rows >> 6) * (t.Kp >> 6);
  };
  auto finish_tsegs = [&](TSegs6& c, int n) {
    int acc = 0;
    for (int i = 0; i < 6; ++i) {
      if (i < n) acc += tseg_tiles(c.s[i]);
      c.s[i].tile_end = acc;
    }
    return acc;
  };

  // ---- prep: We1T, Wk1T, rel pad + topk ----
  TSegs6 pc;
  pc.s[0] = mk_tseg(We1, We1T, FIN, LAT, KP_X, 0);
  pc.s[1] = mk_tseg(Wk1, Wk1T, Dn, LAT, KP_REL, 0);
  pc.s[2] = mk_tseg(rel_emb, rel_bf, Vn, Dn, KP_REL, 1);
  int prep_conv = finish_tsegs(pc, 3);
  prep_kernel<<<prep_conv + Bn / 4, 256, 0, stream>>>(
      pc, prep_conv, logits, rels, rel_emb, pos_keys, neg_keys, x_bf);

  auto mk_gseg = [](const u16* A, const u16* Bt, const float* bias, float* Cf,
                    u16* Cb, const u16* xref, float* part, int M, int N,
                    int Kp, int ldc, int act, int tiles_n) {
    GSeg g;
    g.A = A; g.Bt = Bt; g.bias = bias; g.Cf = Cf; g.Cb = Cb;
    g.xref = xref; g.part = part;
    g.M = M; g.N = N; g.Kp = Kp; g.ldc = ldc; g.act = act;
    g.tiles_n = tiles_n; g.tile_end = 0;
    return g;
  };
  auto gseg_tiles = [](const GSeg& g) {
    return ((g.M + 63) / 64) * g.tiles_n;
  };
  TSegs6 none;
  finish_tsegs(none, 0);
  auto launch_phase = [&](GSeg a, GSeg b, TSegs6 cs, int nconv) {
    GSegs2 gs;
    a.tile_end = gseg_tiles(a);
    b.tile_end = a.tile_end + gseg_tiles(b);
    gs.s[0] = a; gs.s[1] = b;
    int conv_tiles = finish_tsegs(cs, nconv);
    gemm_conv_kernel<<<gs.s[1].tile_end + conv_tiles, 256, 0, stream>>>(gs, cs);
  };

  // A: th = relu(rel_bf@Wk1+bk1) || t1 = tanh(x_bf@We1+be1)  (+6 transposes)
  TSegs6 ac;
  ac.s[0] = mk_tseg(We2, We2T, LAT, LAT, LAT, 0);
  ac.s[1] = mk_tseg(Wd1, Wd1T, LAT, LAT, LAT, 0);
  ac.s[2] = mk_tseg(Wd2, Wd2T, LAT, FIN, LAT, 0);
  ac.s[3] = mk_tseg(Wz1, Wz1T, LAT, LAT, LAT, 0);
  ac.s[4] = mk_tseg(Wz2, Wz2T, LAT, LAT, LAT, 0);
  ac.s[5] = mk_tseg(Wk2, Wk2T, LAT, LAT, LAT, 0);
  launch_phase(
      mk_gseg(rel_bf, Wk1T, bk1, nullptr, th_bf, nullptr, nullptr, Vn, LAT, KP_REL, LAT, 3, 8),
      mk_gseg(x_bf, We1T, be1, nullptr, t1, nullptr, nullptr, Bn, LAT, KP_X, LAT, 1, 8),
      ac, 6);
  // B: proj = th@Wk2+bk2 || zb = tanh(t1@We2+be2)
  launch_phase(
      mk_gseg(th_bf, Wk2T, bk2, proj, nullptr, nullptr, nullptr, Vn, ZD, LAT, ZD, 0, 8),
      mk_gseg(t1, We2T, be2, nullptr, zb, nullptr, nullptr, Bn, ZD, LAT, ZD, 1, 8),
      none, 0);
  // C: t2 = tanh(zb@Wd1+bd1) || t3 = relu(zb@Wz1+bz1)
  launch_phase(
      mk_gseg(zb, Wd1T, bd1, nullptr, t2, nullptr, nullptr, Bn, LAT, ZD, LAT, 1, 8),
      mk_gseg(zb, Wz1T, bz1, nullptr, t3, nullptr, nullptr, Bn, LAT, ZD, LAT, 3, 8),
      none, 0);
  // D: vae partials from sigmoid(t2@Wd2+bd2) vs x_bf || zp = t3@Wz2+bz2
  launch_phase(
      mk_gseg(t2, Wd2T, bd2, nullptr, nullptr, x_bf, vae_part, Bn, FIN, LAT, KP_X, 2, KP_X / 64),
      mk_gseg(t3, Wz2T, bz2, zp_out, nullptr, nullptr, nullptr, Bn, ZD, LAT, ZD, 0, 8),
      none, 0);

  const int n_vae_parts = (Bn / 64) * (KP_X / 64);  // 640

  csl_kernel<<<Bn, 512, 0, stream>>>(zp_out, proj, pos_keys, neg_keys, row_loss);
  finalize_kernel<<<1, 256, 0, stream>>>(vae_part, n_vae_parts, row_loss, Bn, out);
}

// Round 18
// 110.854 us; speedup vs baseline: 1.0709x; 1.0283x over previous
//
#include <hip/hip_runtime.h>
#include <hip/hip_bf16.h>
#include <cfloat>
#include <cmath>

typedef unsigned short u16;
typedef unsigned int uint;
typedef unsigned long long u64;
typedef __attribute__((ext_vector_type(8))) short bf16x8;
typedef __attribute__((ext_vector_type(4))) float f32x4;

// Problem constants
constexpr int Bn  = 4096;
constexpr int Rn  = 1000;
constexpr int Vn  = 2000;
constexpr int Dn  = 300;
constexpr int FIN = 600;
constexpr int LAT = 512;
constexpr int ZD  = 512;
constexpr int DISK_N = 20;
constexpr float TEMP_INV = 1.0f / 0.07f;

constexpr int KP_X   = 640;  // FIN padded to 64-mult
constexpr int KP_REL = 320;  // Dn padded
constexpr int VP     = 2048; // Vn padded

__device__ inline u16 f2b(float v) {
  __hip_bfloat16 h = __float2bfloat16(v);
  return *reinterpret_cast<u16*>(&h);
}
__device__ inline float b2f(u16 u) {
  return __uint_as_float((uint)u << 16);
}

__device__ __forceinline__ void async_copy16(const u16* g, u16* l) {
  __builtin_amdgcn_global_load_lds(
      (const __attribute__((address_space(1))) void*)g,
      (__attribute__((address_space(3))) void*)l, 16, 0, 0);
}

// ---------------------------------------------------------------------------
struct TSeg {
  const float* src;
  u16* dst;
  int K, N, Kp, mode, tile_end;  // mode0: transpose+convert; mode1: pad
};
struct TSegs6 { TSeg s[6]; };
struct GSeg {
  const u16* A;       // M' x Kp (rows padded to 64-mult)
  const u16* Bt;      // N' x Kp
  const float* bias;
  float* Cf;          // fp32 out (or null)
  u16* Cb;            // bf16 out (or null)
  const u16* xref;    // vae ref (bf16, stride ldc)
  float* part;        // vae partials (non-null => vae mode)
  int M, N, Kp, ldc, act, tiles_n, tile_end;
};
struct GSegs2 { GSeg s[2]; };

// ---- conv task (transpose-convert or pad-convert) --------------------------
__device__ void run_conv(const TSegs6& cs, int bid, u16* lds) {
  float (*tile)[65] = reinterpret_cast<float (*)[65]>(lds);
  const int tid = threadIdx.x;
  int si = 0;
  while (si < 5 && bid >= cs.s[si].tile_end) ++si;
  const TSeg sg = cs.s[si];
  int t0 = (si == 0) ? 0 : cs.s[si - 1].tile_end;
  int t = bid - t0;
  int tiles_k = sg.Kp >> 6;
  int tr0 = (t / tiles_k) << 6;
  int tk0 = (t % tiles_k) << 6;

  if (sg.mode == 0) {
#pragma unroll
    for (int i = 0; i < 16; ++i) {
      int idx = tid + i * 256;
      int ko = idx >> 6, no = idx & 63;
      int gk = tk0 + ko, gn = tr0 + no;
      float v = 0.0f;
      if (gk < sg.K && gn < sg.N) v = sg.src[(size_t)gk * sg.N + gn];
      tile[ko][no] = v;
    }
    __syncthreads();
#pragma unroll
    for (int i = 0; i < 16; ++i) {
      int idx = tid + i * 256;
      int ko = idx & 63, no = idx >> 6;
      sg.dst[(size_t)(tr0 + no) * sg.Kp + tk0 + ko] = f2b(tile[ko][no]);
    }
  } else {
#pragma unroll
    for (int i = 0; i < 16; ++i) {
      int idx = tid + i * 256;
      int mo = idx >> 6, ko = idx & 63;
      int gm = tr0 + mo, gk = tk0 + ko;
      float v = 0.0f;
      if (gm < sg.K && gk < sg.N) v = sg.src[(size_t)gm * sg.N + gk];
      sg.dst[(size_t)gm * sg.Kp + gk] = f2b(v);
    }
  }
}

// ---- topk + gather task (4 rows per task, one per wave) --------------------
__device__ void run_topk(int t, const float* __restrict__ logits,
                         const int* __restrict__ rels,
                         const float* __restrict__ rel_emb,
                         int* __restrict__ pos_keys, int* __restrict__ neg_keys,
                         u16* __restrict__ x_bf, u16* lds) {
  uint (*hist)[256] = reinterpret_cast<uint (*)[256]>(lds);
  const int tid = threadIdx.x;
  const int wv = tid >> 6;
  const int lane = tid & 63;
  const int row = t * 4 + wv;
  const float* rowp = logits + (size_t)row * Rn;

  uint s[16];
#pragma unroll
  for (int i = 0; i < 16; ++i) {
    int idx = i * 64 + lane;
    float v = (idx < Rn) ? rowp[idx] : 0.0f;
    uint u = __float_as_uint(v);
    s[i] = u ^ (uint)(((int)u >> 31) | 0x80000000);
  }
  const bool v15 = (lane < (Rn - 15 * 64));

  uint pref = 0;
  int r = DISK_N;
#pragma unroll
  for (int pass = 0; pass < 4; ++pass) {
    const int shift = 24 - pass * 8;
    *(uint4*)&hist[wv][lane * 4] = make_uint4(0, 0, 0, 0);
    __syncthreads();
#pragma unroll
    for (int i = 0; i < 16; ++i) {
      bool valid = (i < 15) || v15;
      bool match = valid &&
          (pass == 0 || ((s[i] >> (shift + 8)) == (pref >> (shift + 8))));
      if (match) atomicAdd(&hist[wv][(s[i] >> shift) & 255], 1u);
    }
    __syncthreads();
    uint4 c = *(uint4*)&hist[wv][lane * 4];
    uint t1 = c.x + c.y, t2 = t1 + c.z, t3 = t2 + c.w;
    uint sc = t3;
#pragma unroll
    for (int off = 1; off <= 32; off <<= 1) {
      uint o = __shfl_up(sc, off);
      if (lane >= off) sc += o;
    }
    uint excl = sc - t3;
    uint i0 = excl + c.x, i1 = excl + t1, i2 = excl + t2, i3 = excl + t3;
    u64 m = __ballot(i3 >= (uint)r);
    int fl = __ffsll((unsigned long long)m) - 1;
    int j = (i0 >= (uint)r) ? 0 : (i1 >= (uint)r) ? 1 : (i2 >= (uint)r) ? 2 : 3;
    uint bexcl = (j == 0) ? excl : (j == 1) ? i0 : (j == 2) ? i1 : i2;
    int bin = lane * 4 + j;
    bin = __shfl(bin, fl);
    bexcl = __shfl(bexcl, fl);
    r -= (int)bexcl;
    pref |= (uint)bin << shift;
    __syncthreads();
  }
  const uint T = pref;

  int cl = 0;
#pragma unroll
  for (int i = 0; i < 16; ++i) {
    bool valid = (i < 15) || v15;
    if (valid && s[i] < T) cl++;
  }
  uint scl = (uint)cl;
#pragma unroll
  for (int off = 1; off <= 32; off <<= 1) {
    uint o = __shfl_up(scl, off);
    if (lane >= off) scl += o;
  }
  int pos = (int)(scl - (uint)cl);
  int* nk = neg_keys + (size_t)row * DISK_N;
#pragma unroll
  for (int i = 0; i < 16; ++i) {
    bool valid = (i < 15) || v15;
    if (valid && s[i] < T) { nk[pos] = rels[(i * 64 + lane) * 2 + 1]; pos++; }
  }
  {
    int base = DISK_N - r;
    int need = r, taken = 0;
#pragma unroll
    for (int i = 0; i < 16; ++i) {
      if (need > 0) {
        bool valid = (i < 15) || v15;
        bool eq = valid && (s[i] == T);
        u64 mm = __ballot(eq);
        int before = __popcll(mm & ((1ull << lane) - 1ull));
        if (eq && before < need) nk[base + taken + before] = rels[(i * 64 + lane) * 2 + 1];
        int cnt = __popcll(mm);
        int take = cnt < need ? cnt : need;
        need -= take;
        taken += take;
      }
    }
  }

  u64 b1 = 0;
#pragma unroll
  for (int i = 0; i < 16; ++i) {
    bool valid = (i < 15) || v15;
    uint k = valid ? s[i] : 0u;
    u64 p = ((u64)k << 10) | (u64)(1023 - (i * 64 + lane));
    b1 = p > b1 ? p : b1;
  }
#pragma unroll
  for (int off = 1; off < 64; off <<= 1) {
    u64 o = __shfl_xor(b1, off);
    b1 = o > b1 ? o : b1;
  }
  int idx0 = 1023 - (int)(b1 & 1023);
  u64 b2 = 0;
#pragma unroll
  for (int i = 0; i < 16; ++i) {
    int idx = i * 64 + lane;
    bool valid = ((i < 15) || v15) && (idx != idx0);
    uint k = valid ? s[i] : 0u;
    u64 p = ((u64)k << 10) | (u64)(1023 - idx);
    b2 = p > b2 ? p : b2;
  }
#pragma unroll
  for (int off = 1; off < 64; off <<= 1) {
    u64 o = __shfl_xor(b2, off);
    b2 = o > b2 ? o : b2;
  }
  int idx1 = 1023 - (int)(b2 & 1023);

  int k0 = rels[idx0 * 2 + 1];
  int k1 = rels[idx1 * 2 + 1];
  if (lane == 0) {
    pos_keys[row * 2 + 0] = k0;
    pos_keys[row * 2 + 1] = k1;
  }

  const float* e0 = rel_emb + (size_t)k0 * Dn;
  const float* e1 = rel_emb + (size_t)k1 * Dn;
  u16* xbb = x_bf + (size_t)row * KP_X;
  for (int d = lane; d < KP_X; d += 64) {
    float v = 0.0f;
    if (d < Dn) v = e0[d];
    else if (d < FIN) v = e1[d - Dn];
    xbb[d] = f2b(v);
  }
}

// ---- GEMM task: 64x64 tile, 4 waves (2x2), BK=64, SINGLE-buffer LDS -------
// 16 KB LDS + launch_bounds(256,8) -> 8 blocks/CU (32 waves): TLP hides the
// per-iter stage latency. (Established local optimum: BK128/dbuf/big-tile/
// reg-direct all measured worse; occupancy is the dominant lever here.)
__device__ void run_gemm(const GSeg& sg, int t, u16* lds) {
  u16* As = lds;           // [4096]
  u16* Bs = lds + 4096;    // [4096]

  const int tid = threadIdx.x;
  const int lane = tid & 63;
  const int w = tid >> 6;
  const int wm = (w >> 1) * 32;
  const int wn = (w & 1) * 32;
  const int m0 = (t / sg.tiles_n) * 64;
  const int n0 = (t % sg.tiles_n) * 64;
  const int Kp = sg.Kp;

  const int rA = lane >> 3;
  const int cC = ((lane & 7) ^ rA) * 8;
  const u16* gA = sg.A + (size_t)(m0 + w * 16 + rA) * Kp + cC;
  const u16* gB = sg.Bt + (size_t)(n0 + w * 16 + rA) * Kp + cC;

  auto stage = [&](int k0) {
#pragma unroll
    for (int j = 0; j < 2; ++j) {
      async_copy16(gA + (size_t)j * 8 * Kp + k0, As + (w * 16 + j * 8) * 64);
      async_copy16(gB + (size_t)j * 8 * Kp + k0, Bs + (w * 16 + j * 8) * 64);
    }
  };

  f32x4 acc[2][2];
#pragma unroll
  for (int i = 0; i < 2; ++i)
#pragma unroll
    for (int j = 0; j < 2; ++j) acc[i][j] = (f32x4)(0.0f);

  const int r = lane & 15;
  const int kq = lane >> 4;

  const int NT = Kp >> 6;
  for (int tt = 0; tt < NT; ++tt) {
    stage(tt << 6);
    __syncthreads();  // compiler emits vmcnt(0) drain before barrier
#pragma unroll
    for (int ks = 0; ks < 2; ++ks) {
      const int kk = ks * 32 + kq * 8;
      const int xm = (r & 7) << 3;
      bf16x8 a0 = *(const bf16x8*)(As + (wm + r) * 64 + (kk ^ xm));
      bf16x8 a1 = *(const bf16x8*)(As + (wm + 16 + r) * 64 + (kk ^ xm));
      bf16x8 b0 = *(const bf16x8*)(Bs + (wn + r) * 64 + (kk ^ xm));
      bf16x8 b1 = *(const bf16x8*)(Bs + (wn + 16 + r) * 64 + (kk ^ xm));
      acc[0][0] = __builtin_amdgcn_mfma_f32_16x16x32_bf16(a0, b0, acc[0][0], 0, 0, 0);
      acc[0][1] = __builtin_amdgcn_mfma_f32_16x16x32_bf16(a0, b1, acc[0][1], 0, 0, 0);
      acc[1][0] = __builtin_amdgcn_mfma_f32_16x16x32_bf16(a1, b0, acc[1][0], 0, 0, 0);
      acc[1][1] = __builtin_amdgcn_mfma_f32_16x16x32_bf16(a1, b1, acc[1][1], 0, 0, 0);
    }
    __syncthreads();  // WAR before next stage overwrites
  }

  const int cr = lane >> 4;
  const int cc = lane & 15;
  const bool fuse_vae = (sg.part != nullptr);
  float vsum = 0.0f;
#pragma unroll
  for (int mi = 0; mi < 2; ++mi) {
#pragma unroll
    for (int ni = 0; ni < 2; ++ni) {
      int gn = n0 + wn + ni * 16 + cc;
      if (gn >= sg.N) continue;
      float bv = sg.bias[gn];
#pragma unroll
      for (int rr = 0; rr < 4; ++rr) {
        int gm = m0 + wm + mi * 16 + cr * 4 + rr;
        if (gm >= sg.M) continue;
        float vv = acc[mi][ni][rr] + bv;
        if (sg.act == 1) vv = tanhf(vv);
        else if (sg.act == 2) vv = 1.0f / (1.0f + expf(-vv));
        else if (sg.act == 3) vv = fmaxf(vv, 0.0f);
        if (fuse_vae) {
          float xr = b2f(sg.xref[(size_t)gm * sg.ldc + gn]);
          float d = xr - vv;
          vsum = fmaf(d, d, vsum);
        } else if (sg.Cb) {
          sg.Cb[(size_t)gm * sg.ldc + gn] = f2b(vv);
        } else {
          sg.Cf[(size_t)gm * sg.ldc + gn] = vv;
        }
      }
    }
  }
  if (fuse_vae) {
    float* red = (float*)lds;
    red[tid] = vsum;
    __syncthreads();
    for (int off = 128; off >= 1; off >>= 1) {
      if (tid < off) red[tid] += red[tid + off];
      __syncthreads();
    }
    if (tid == 0) sg.part[t] = red[0];
  }
}

// ---------------------------------------------------------------------------
__global__ __launch_bounds__(256) void prep_kernel(
    TSegs6 cs, int conv_end,
    const float* __restrict__ logits, const int* __restrict__ rels,
    const float* __restrict__ rel_emb,
    int* __restrict__ pos_keys, int* __restrict__ neg_keys,
    u16* __restrict__ x_bf) {
  __shared__ u16 lds[8320];
  if ((int)blockIdx.x < conv_end) {
    run_conv(cs, blockIdx.x, lds);
  } else {
    run_topk(blockIdx.x - conv_end, logits, rels, rel_emb, pos_keys, neg_keys,
             x_bf, lds);
  }
}

// ---------------------------------------------------------------------------
__global__ __launch_bounds__(256, 8) void gemm_conv_kernel(GSegs2 gs, TSegs6 cs) {
  __shared__ u16 lds[8320];  // 16.6 KB: gemm uses 16 KB, conv uses all
  const int bid = blockIdx.x;
  if (bid < gs.s[1].tile_end) {
    const int si = (bid >= gs.s[0].tile_end) ? 1 : 0;
    const GSeg sg = gs.s[si];
    const int t = bid - (si ? gs.s[0].tile_end : 0);
    run_gemm(sg, t, lds);
  } else {
    run_conv(cs, bid - gs.s[1].tile_end, lds);
  }
}

// ---------------------------------------------------------------------------
// csl: ONE row per block; 4 waves split the 21 keys (<=6 each).
// ---------------------------------------------------------------------------
__global__ __launch_bounds__(256) void csl_kernel(
    const float* __restrict__ zp, const float* __restrict__ proj,
    const int* __restrict__ pos_keys, const int* __restrict__ neg_keys,
    float* __restrict__ row_loss) {
  __shared__ float lgs[24];
  const int tid = threadIdx.x;
  const int wv = tid >> 6;
  const int lane = tid & 63;
  const int b = blockIdx.x;

  const float* z = zp + (size_t)b * ZD;
  float zz[8];
#pragma unroll
  for (int q = 0; q < 2; ++q) {
    int base = (lane + q * 64) * 4;
    float2 a = *(const float2*)(z + base);
    float2 c = *(const float2*)(z + base + 2);
    zz[q * 4 + 0] = a.x; zz[q * 4 + 1] = a.y;
    zz[q * 4 + 2] = c.x; zz[q * 4 + 3] = c.y;
  }

  for (int k = wv; k < 21; k += 4) {
    int key = (k == 0) ? pos_keys[b * 2] : neg_keys[b * DISK_N + (k - 1)];
    const float4* p4 = (const float4*)(proj + (size_t)key * ZD);
    float4 pa = p4[lane];
    float4 pb = p4[lane + 64];
    float acc = zz[0] * pa.x;
    acc = fmaf(zz[1], pa.y, acc);
    acc = fmaf(zz[2], pa.z, acc);
    acc = fmaf(zz[3], pa.w, acc);
    acc = fmaf(zz[4], pb.x, acc);
    acc = fmaf(zz[5], pb.y, acc);
    acc = fmaf(zz[6], pb.z, acc);
    acc = fmaf(zz[7], pb.w, acc);
#pragma unroll
    for (int off = 32; off >= 1; off >>= 1) acc += __shfl_xor(acc, off);
    if (lane == 0) lgs[k] = acc * TEMP_INV;
  }
  __syncthreads();

  if (wv == 0) {
    float v = (lane < 21) ? lgs[lane] : -FLT_MAX;
    float m = v;
#pragma unroll
    for (int off = 32; off >= 1; off >>= 1) m = fmaxf(m, __shfl_xor(m, off));
    float e = (lane < 21) ? expf(v - m) : 0.0f;
    float se = e;
#pragma unroll
    for (int off = 32; off >= 1; off >>= 1) se += __shfl_xor(se, off);
    if (lane == 0) row_loss[b] = m + logf(se) - lgs[0];
  }
}

// ---------------------------------------------------------------------------
__global__ __launch_bounds__(256) void finalize_kernel(
    const float* __restrict__ vae_partials, int n_vae,
    const float* __restrict__ row_loss, int n_rows, float* __restrict__ out) {
  __shared__ float red[256];
  const int tid = threadIdx.x;

  float s = 0.0f;
  for (int i = tid; i < n_vae; i += 256) s += vae_partials[i];
  red[tid] = s;
  __syncthreads();
  for (int off = 128; off >= 1; off >>= 1) {
    if (tid < off) red[tid] += red[tid + off];
    __syncthreads();
  }
  float loss_vae = red[0] * (1.0f / (float)FIN);
  __syncthreads();

  float s2 = 0.0f;
  for (int i = tid; i < n_rows; i += 256) s2 += row_loss[i];
  red[tid] = s2;
  __syncthreads();
  for (int off = 128; off >= 1; off >>= 1) {
    if (tid < off) red[tid] += red[tid + off];
    __syncthreads();
  }
  if (tid == 0) {
    out[0] = loss_vae;
    out[1] = red[0];
  }
  for (int i = tid; i < ZD; i += 256) out[2 + i] = 0.0f;
}

// ---------------------------------------------------------------------------
extern "C" void kernel_launch(void* const* d_in, const int* in_sizes, int n_in,
                              void* d_out, int out_size, void* d_ws,
                              size_t ws_size, hipStream_t stream) {
  const float* logits = (const float*)d_in[0];
  const int*   rels   = (const int*)d_in[1];
  const float* rel_emb= (const float*)d_in[2];
  const float* We1 = (const float*)d_in[3];  const float* be1 = (const float*)d_in[4];
  const float* We2 = (const float*)d_in[5];  const float* be2 = (const float*)d_in[6];
  const float* Wd1 = (const float*)d_in[7];  const float* bd1 = (const float*)d_in[8];
  const float* Wd2 = (const float*)d_in[9];  const float* bd2 = (const float*)d_in[10];
  const float* Wz1 = (const float*)d_in[11]; const float* bz1 = (const float*)d_in[12];
  const float* Wz2 = (const float*)d_in[13]; const float* bz2 = (const float*)d_in[14];
  const float* Wk1 = (const float*)d_in[19]; const float* bk1 = (const float*)d_in[20];
  const float* Wk2 = (const float*)d_in[21]; const float* bk2 = (const float*)d_in[22];

  float* out = (float*)d_out;

  char* ws = (char*)d_ws;
  size_t off = 0;
  auto walloc = [&](size_t bytes) -> void* {
    void* p = ws + off;
    off = (off + bytes + 255) & ~(size_t)255;
    return p;
  };
  int*   pos_keys = (int*)walloc((size_t)Bn * 2 * sizeof(int));
  int*   neg_keys = (int*)walloc((size_t)Bn * DISK_N * sizeof(int));
  float* proj     = (float*)walloc((size_t)Vn * ZD * sizeof(float));
  u16*   x_bf     = (u16*)walloc((size_t)Bn * KP_X * 2);
  u16*   t1       = (u16*)walloc((size_t)Bn * LAT * 2);
  u16*   zb       = (u16*)walloc((size_t)Bn * LAT * 2);
  u16*   t2       = (u16*)walloc((size_t)Bn * LAT * 2);
  u16*   t3       = (u16*)walloc((size_t)Bn * LAT * 2);
  u16*   th_bf    = (u16*)walloc((size_t)VP * LAT * 2);
  u16*   rel_bf   = (u16*)walloc((size_t)VP * KP_REL * 2);
  u16*   We1T     = (u16*)walloc((size_t)LAT * KP_X * 2);
  u16*   We2T     = (u16*)walloc((size_t)LAT * LAT * 2);
  u16*   Wd1T     = (u16*)walloc((size_t)LAT * LAT * 2);
  u16*   Wd2T     = (u16*)walloc((size_t)KP_X * LAT * 2);
  u16*   Wz1T     = (u16*)walloc((size_t)LAT * LAT * 2);
  u16*   Wz2T     = (u16*)walloc((size_t)LAT * LAT * 2);
  u16*   Wk1T     = (u16*)walloc((size_t)LAT * KP_REL * 2);
  u16*   Wk2T     = (u16*)walloc((size_t)LAT * LAT * 2);
  float* vae_part = (float*)walloc(1024 * sizeof(float));
  float* row_loss = (float*)walloc((size_t)Bn * sizeof(float));
  (void)ws_size; (void)in_sizes; (void)n_in; (void)out_size;

  float* zp_out = out + 2 + ZD;

  auto mk_tseg = [](const float* s, u16* d, int K, int N, int Kp, int mode) {
    TSeg t;
    t.src = s; t.dst = d; t.K = K; t.N = N; t.Kp = Kp; t.mode = mode;
    t.tile_end = 0;
    return t;
  };
  auto tseg_tiles = [](const TSeg& t) {
    int rows = (t.mode == 0) ? ((t.N + 63) & ~63) : VP;
    return (rows >> 6) * (t.Kp >> 6);
  };
  auto finish_tsegs = [&](TSegs6& c, int n) {
    int acc = 0;
    for (int i = 0; i < 6; ++i) {
      if (i < n) acc += tseg_tiles(c.s[i]);
      c.s[i].tile_end = acc;
    }
    return acc;
  };

  // ---- prep: We1T, Wk1T, rel pad + topk ----
  TSegs6 pc;
  pc.s[0] = mk_tseg(We1, We1T, FIN, LAT, KP_X, 0);
  pc.s[1] = mk_tseg(Wk1, Wk1T, Dn, LAT, KP_REL, 0);
  pc.s[2] = mk_tseg(rel_emb, rel_bf, Vn, Dn, KP_REL, 1);
  int prep_conv = finish_tsegs(pc, 3);
  prep_kernel<<<prep_conv + Bn / 4, 256, 0, stream>>>(
      pc, prep_conv, logits, rels, rel_emb, pos_keys, neg_keys, x_bf);

  auto mk_gseg = [](const u16* A, const u16* Bt, const float* bias, float* Cf,
                    u16* Cb, const u16* xref, float* part, int M, int N,
                    int Kp, int ldc, int act, int tiles_n) {
    GSeg g;
    g.A = A; g.Bt = Bt; g.bias = bias; g.Cf = Cf; g.Cb = Cb;
    g.xref = xref; g.part = part;
    g.M = M; g.N = N; g.Kp = Kp; g.ldc = ldc; g.act = act;
    g.tiles_n = tiles_n; g.tile_end = 0;
    return g;
  };
  auto gseg_tiles = [](const GSeg& g) {
    return ((g.M + 63) / 64) * g.tiles_n;
  };
  TSegs6 none;
  finish_tsegs(none, 0);
  auto launch_phase = [&](GSeg a, GSeg b, TSegs6 cs, int nconv) {
    GSegs2 gs;
    a.tile_end = gseg_tiles(a);
    b.tile_end = a.tile_end + gseg_tiles(b);
    gs.s[0] = a; gs.s[1] = b;
    int conv_tiles = finish_tsegs(cs, nconv);
    gemm_conv_kernel<<<gs.s[1].tile_end + conv_tiles, 256, 0, stream>>>(gs, cs);
  };

  // A: th = relu(rel_bf@Wk1+bk1) || t1 = tanh(x_bf@We1+be1)  (+6 transposes)
  TSegs6 ac;
  ac.s[0] = mk_tseg(We2, We2T, LAT, LAT, LAT, 0);
  ac.s[1] = mk_tseg(Wd1, Wd1T, LAT, LAT, LAT, 0);
  ac.s[2] = mk_tseg(Wd2, Wd2T, LAT, FIN, LAT, 0);
  ac.s[3] = mk_tseg(Wz1, Wz1T, LAT, LAT, LAT, 0);
  ac.s[4] = mk_tseg(Wz2, Wz2T, LAT, LAT, LAT, 0);
  ac.s[5] = mk_tseg(Wk2, Wk2T, LAT, LAT, LAT, 0);
  launch_phase(
      mk_gseg(rel_bf, Wk1T, bk1, nullptr, th_bf, nullptr, nullptr, Vn, LAT, KP_REL, LAT, 3, 8),
      mk_gseg(x_bf, We1T, be1, nullptr, t1, nullptr, nullptr, Bn, LAT, KP_X, LAT, 1, 8),
      ac, 6);
  // B: proj = th@Wk2+bk2 || zb = tanh(t1@We2+be2)
  launch_phase(
      mk_gseg(th_bf, Wk2T, bk2, proj, nullptr, nullptr, nullptr, Vn, ZD, LAT, ZD, 0, 8),
      mk_gseg(t1, We2T, be2, nullptr, zb, nullptr, nullptr, Bn, ZD, LAT, ZD, 1, 8),
      none, 0);
  // C: t2 = tanh(zb@Wd1+bd1) || t3 = relu(zb@Wz1+bz1)
  launch_phase(
      mk_gseg(zb, Wd1T, bd1, nullptr, t2, nullptr, nullptr, Bn, LAT, ZD, LAT, 1, 8),
      mk_gseg(zb, Wz1T, bz1, nullptr, t3, nullptr, nullptr, Bn, LAT, ZD, LAT, 3, 8),
      none, 0);
  // D: vae partials from sigmoid(t2@Wd2+bd2) vs x_bf || zp = t3@Wz2+bz2
  launch_phase(
      mk_gseg(t2, Wd2T, bd2, nullptr, nullptr, x_bf, vae_part, Bn, FIN, LAT, KP_X, 2, KP_X / 64),
      mk_gseg(t3, Wz2T, bz2, zp_out, nullptr, nullptr, nullptr, Bn, ZD, LAT, ZD, 0, 8),
      none, 0);

  const int n_vae_parts = (Bn / 64) * (KP_X / 64);  // 640

  csl_kernel<<<Bn, 256, 0, stream>>>(zp_out, proj, pos_keys, neg_keys, row_loss);
  finalize_kernel<<<1, 256, 0, stream>>>(vae_part, n_vae_parts, row_loss, Bn, out);
}